// Round 5
// baseline (483.804 us; speedup 1.0000x reference)
//
#include <hip/hip_runtime.h>
#include <math.h>

#define NE 22   // electrons
#define NA 11   // atoms
#define HD 8    // HID
#define H2 16   // 2*HID
#define QN 22   // QNUM
#define NL 6    // layers
#define CPAD 12 // atom conv position slots (11 + 1 pad)
#define CSTR 17 // conv row stride in floats (breaks pow2 bank pattern)

struct QCS { float c[QN]; float s[QN]; };

// wave-uniform broadcast (lane idx compile-time-uniform across wave)
#define RL(v, l) __uint_as_float(__builtin_amdgcn_readlane(__float_as_uint(v), (l)))

__device__ __forceinline__ float block_reduce_sum(float v, float* red, int tid) {
  red[tid] = v;
  __syncthreads();
  for (int off = 128; off > 0; off >>= 1) {
    if (tid < off) red[tid] += red[tid + off];
    __syncthreads();
  }
  float s = red[0];
  __syncthreads();
  return s;
}

// fully-unrolled LN: static indices only -> registers, no scratch
template<int N>
__device__ __forceinline__ void ln_t(const float* x, const float* __restrict__ g,
                                     const float* __restrict__ bb, float* o) {
  float m = 0.f;
  #pragma unroll
  for (int i = 0; i < N; i++) m += x[i];
  m *= (1.0f / (float)N);
  float v = 0.f;
  #pragma unroll
  for (int i = 0; i < N; i++) { float d = x[i] - m; v += d * d; }
  v *= (1.0f / (float)N);
  float is = 1.0f / sqrtf(v + 1e-5f);
  #pragma unroll
  for (int i = 0; i < N; i++) o[i] = (x[i] - m) * is * g[i] + bb[i];
}

__device__ __forceinline__ double det3(double a, double b, double c,
                                       double d, double e, double f,
                                       double g, double h, double i) {
  return a * (e * i - f * h) - b * (d * i - f * g) + c * (d * h - e * g);
}

// ============ fused: per-electron transformer (22 blocks) + last-block tail ============
__global__ __launch_bounds__(256) void net_kernel(
    const float* __restrict__ pos_a, const int* __restrict__ ix_a,
    const int* __restrict__ pos_ix, const int* __restrict__ atom_ix,
    const float* __restrict__ rpos_w, const float* __restrict__ emb_w,
    const float* __restrict__ emb_b,
    const float* __restrict__ Wq, const float* __restrict__ bq,
    const float* __restrict__ Wk, const float* __restrict__ bk,
    const float* __restrict__ Wv, const float* __restrict__ bv,
    const float* __restrict__ Wo, const float* __restrict__ bo,
    const float* __restrict__ W1, const float* __restrict__ b1,
    const float* __restrict__ W2, const float* __restrict__ b2,
    const float* __restrict__ ln1_g, const float* __restrict__ ln1_b,
    const float* __restrict__ ln2_g, const float* __restrict__ ln2_b,
    const float* __restrict__ Wi, const float* __restrict__ bi,
    const float* __restrict__ ni_g, const float* __restrict__ ni_b,
    const float* __restrict__ conv_a_w, const float* __restrict__ conv_e_w,
    float* __restrict__ seq_ws, float* __restrict__ rae_ws,
    int* __restrict__ counter, float* __restrict__ xf_out)
{
  const int e = blockIdx.x;
  const int tid = threadIdx.x;
  const int a = tid >> 3;      // 0..31, active < 11
  const int h = tid & 7;
  const bool act = (a < NA);

  // ---- layers LDS ----
  __shared__ __align__(16) float sseq[NA][HD];
  __shared__ __align__(16) float sx[NA][HD];
  __shared__ __align__(16) float sq_[NA][HD];
  __shared__ __align__(16) float sk_[NA][HD];
  __shared__ __align__(16) float sv_[NA][HD];
  __shared__ __align__(16) float sav[NA][HD];
  __shared__ float ss[NA][12];
  __shared__ __align__(16) float sh_[NA][32];
  __shared__ int s_win;

  // ---- embedding ----
  float amp_a = 0.f;
  if (act) {
    amp_a = (float)ix_a[a];
    int p = pos_ix[e], am = atom_ix[e];
    float d0 = rpos_w[p*3+0] + pos_a[am*3+0] - pos_a[a*3+0];
    float d1 = rpos_w[p*3+1] + pos_a[am*3+1] - pos_a[a*3+1];
    float d2 = rpos_w[p*3+2] + pos_a[am*3+2] - pos_a[a*3+2];
    float rae = sqrtf(d0*d0 + d1*d1 + d2*d2);
    float s = emb_b[h] + d0*emb_w[h*4+0] + d1*emb_w[h*4+1]
            + d2*emb_w[h*4+2] + rae*emb_w[h*4+3];
    sseq[a][h] = s;
    if (h == 0) rae_ws[e*NA + a] = rae;
  }
  __syncthreads();

  const float iscale = 0.35355339059327373f;  // 1/sqrt(8)
  for (int l = 0; l < NL; l++) {
    float wq[8], wk[8], wv[8], wo[8], w1v[4][8], w2v[32];
    float bqv=0, bkv=0, bvv=0, bov=0, b1v[4]={0,0,0,0}, b2v=0, g1=0, be1=0, g2=0, be2=0;
    if (act) {
      const float4* q4 = (const float4*)(Wq + l*64 + h*8);
      float4 t0 = q4[0], t1 = q4[1];
      wq[0]=t0.x; wq[1]=t0.y; wq[2]=t0.z; wq[3]=t0.w; wq[4]=t1.x; wq[5]=t1.y; wq[6]=t1.z; wq[7]=t1.w;
      const float4* k4 = (const float4*)(Wk + l*64 + h*8);
      t0 = k4[0]; t1 = k4[1];
      wk[0]=t0.x; wk[1]=t0.y; wk[2]=t0.z; wk[3]=t0.w; wk[4]=t1.x; wk[5]=t1.y; wk[6]=t1.z; wk[7]=t1.w;
      const float4* v4 = (const float4*)(Wv + l*64 + h*8);
      t0 = v4[0]; t1 = v4[1];
      wv[0]=t0.x; wv[1]=t0.y; wv[2]=t0.z; wv[3]=t0.w; wv[4]=t1.x; wv[5]=t1.y; wv[6]=t1.z; wv[7]=t1.w;
      const float4* o4 = (const float4*)(Wo + l*64 + h*8);
      t0 = o4[0]; t1 = o4[1];
      wo[0]=t0.x; wo[1]=t0.y; wo[2]=t0.z; wo[3]=t0.w; wo[4]=t1.x; wo[5]=t1.y; wo[6]=t1.z; wo[7]=t1.w;
      #pragma unroll
      for (int j = 0; j < 4; j++) {
        const float4* w14 = (const float4*)(W1 + l*256 + (j*8 + h)*8);
        float4 u0 = w14[0], u1 = w14[1];
        w1v[j][0]=u0.x; w1v[j][1]=u0.y; w1v[j][2]=u0.z; w1v[j][3]=u0.w;
        w1v[j][4]=u1.x; w1v[j][5]=u1.y; w1v[j][6]=u1.z; w1v[j][7]=u1.w;
      }
      const float4* w24 = (const float4*)(W2 + l*256 + h*32);
      #pragma unroll
      for (int j = 0; j < 8; j++) {
        float4 u = w24[j];
        w2v[j*4+0]=u.x; w2v[j*4+1]=u.y; w2v[j*4+2]=u.z; w2v[j*4+3]=u.w;
      }
      bqv = bq[l*8+h]; bkv = bk[l*8+h]; bvv = bv[l*8+h]; bov = bo[l*8+h];
      #pragma unroll
      for (int j = 0; j < 4; j++) b1v[j] = b1[l*32 + j*8 + h];
      b2v = b2[l*8+h];
      g1 = ln1_g[l*8+h]; be1 = ln1_b[l*8+h];
      g2 = ln2_g[l*8+h]; be2 = ln2_b[l*8+h];
    }

    // x = amp * seq
    float xah = 0.f;
    if (act) { xah = amp_a * sseq[a][h]; sx[a][h] = xah; }
    __syncthreads();

    // qkv
    if (act) {
      float4 r0 = *(const float4*)&sx[a][0];
      float4 r1 = *(const float4*)&sx[a][4];
      float xr[8] = { r0.x, r0.y, r0.z, r0.w, r1.x, r1.y, r1.z, r1.w };
      float q_ = bqv, k_ = bkv, v_ = bvv;
      #pragma unroll
      for (int h2 = 0; h2 < 8; h2++) {
        q_ += xr[h2]*wq[h2];
        k_ += xr[h2]*wk[h2];
        v_ += xr[h2]*wv[h2];
      }
      sq_[a][h] = q_; sk_[a][h] = k_; sv_[a][h] = v_;
    }
    __syncthreads();

    // scores: thread (a,h) does ka=h; h<3 also ka=8+h
    if (act) {
      float4 q0 = *(const float4*)&sq_[a][0];
      float4 q1 = *(const float4*)&sq_[a][4];
      {
        int ka = h;
        float4 k0 = *(const float4*)&sk_[ka][0];
        float4 k1 = *(const float4*)&sk_[ka][4];
        ss[a][ka] = iscale * (q0.x*k0.x + q0.y*k0.y + q0.z*k0.z + q0.w*k0.w
                            + q1.x*k1.x + q1.y*k1.y + q1.z*k1.z + q1.w*k1.w);
      }
      if (h < 3) {
        int ka = 8 + h;
        float4 k0 = *(const float4*)&sk_[ka][0];
        float4 k1 = *(const float4*)&sk_[ka][4];
        ss[a][ka] = iscale * (q0.x*k0.x + q0.y*k0.y + q0.z*k0.z + q0.w*k0.w
                            + q1.x*k1.x + q1.y*k1.y + q1.z*k1.z + q1.w*k1.w);
      }
    }
    __syncthreads();

    // softmax + AV for own h
    if (act) {
      float sc[NA], mx = -1e30f;
      #pragma unroll
      for (int ka = 0; ka < NA; ka++) { sc[ka] = ss[a][ka]; mx = fmaxf(mx, sc[ka]); }
      float den = 0.f;
      #pragma unroll
      for (int ka = 0; ka < NA; ka++) { sc[ka] = expf(sc[ka] - mx); den += sc[ka]; }
      float inv_den = 1.0f / den;
      float avh = 0.f;
      #pragma unroll
      for (int ka = 0; ka < NA; ka++) avh += sc[ka] * sv_[ka][h];
      sav[a][h] = avh * inv_den;
    }
    __syncthreads();

    // O-proj + residual (keep own element in register)
    float xr_own = 0.f;
    if (act) {
      float4 r0 = *(const float4*)&sav[a][0];
      float4 r1 = *(const float4*)&sav[a][4];
      float av[8] = { r0.x, r0.y, r0.z, r0.w, r1.x, r1.y, r1.z, r1.w };
      float t = bov;
      #pragma unroll
      for (int h2 = 0; h2 < 8; h2++) t += av[h2]*wo[h2];
      xr_own = xah + t;
      sq_[a][h] = xr_own;
    }
    __syncthreads();

    // LN1: mean/var from float4 row reads, own element from register (no dyn index)
    float xnh = 0.f;
    if (act) {
      float4 r0 = *(const float4*)&sq_[a][0];
      float4 r1 = *(const float4*)&sq_[a][4];
      float m = (r0.x+r0.y+r0.z+r0.w+r1.x+r1.y+r1.z+r1.w) * 0.125f;
      float d, v = 0.f;
      d=r0.x-m; v+=d*d; d=r0.y-m; v+=d*d; d=r0.z-m; v+=d*d; d=r0.w-m; v+=d*d;
      d=r1.x-m; v+=d*d; d=r1.y-m; v+=d*d; d=r1.z-m; v+=d*d; d=r1.w-m; v+=d*d;
      v *= 0.125f;
      float is = 1.0f / sqrtf(v + 1e-5f);
      xnh = (xr_own - m) * is * g1 + be1;
      sk_[a][h] = xnh;
    }
    __syncthreads();

    // FFN hidden
    if (act) {
      float4 r0 = *(const float4*)&sk_[a][0];
      float4 r1 = *(const float4*)&sk_[a][4];
      float xn[8] = { r0.x, r0.y, r0.z, r0.w, r1.x, r1.y, r1.z, r1.w };
      #pragma unroll
      for (int j = 0; j < 4; j++) {
        float t = b1v[j];
        #pragma unroll
        for (int h2 = 0; h2 < 8; h2++) t += xn[h2]*w1v[j][h2];
        sh_[a][j*8+h] = fmaxf(t, 0.f);
      }
    }
    __syncthreads();

    // FFN out + residual (own element in register)
    float xr2_own = 0.f;
    if (act) {
      float f2 = b2v;
      #pragma unroll
      for (int j = 0; j < 8; j++) {
        float4 hv = *(const float4*)&sh_[a][j*4];
        f2 += hv.x*w2v[j*4+0] + hv.y*w2v[j*4+1] + hv.z*w2v[j*4+2] + hv.w*w2v[j*4+3];
      }
      xr2_own = xnh + f2;
      sq_[a][h] = xr2_own;
    }
    __syncthreads();

    // LN2 -> sseq
    if (act) {
      float4 r0 = *(const float4*)&sq_[a][0];
      float4 r1 = *(const float4*)&sq_[a][4];
      float m = (r0.x+r0.y+r0.z+r0.w+r1.x+r1.y+r1.z+r1.w) * 0.125f;
      float d, v = 0.f;
      d=r0.x-m; v+=d*d; d=r0.y-m; v+=d*d; d=r0.z-m; v+=d*d; d=r0.w-m; v+=d*d;
      d=r1.x-m; v+=d*d; d=r1.y-m; v+=d*d; d=r1.z-m; v+=d*d; d=r1.w-m; v+=d*d;
      v *= 0.125f;
      float is = 1.0f / sqrtf(v + 1e-5f);
      sseq[a][h] = (xr2_own - m) * is * g2 + be2;
    }
    __syncthreads();

  }

  if (act) seq_ws[e*NA*HD + a*HD + h] = sseq[a][h];

  // ---- last-block-wins: the block whose atomicAdd returns NE-1 runs the tail ----
  __threadfence();
  if (tid == 0) s_win = (atomicAdd(counter, 1) == NE - 1) ? 1 : 0;
  __syncthreads();
  if (!s_win) return;
  __threadfence();

  // ======================= TAIL (256 threads, one block) =======================
  const int lane = tid & 63;
  const int b = tid / NA;
  const int a2i = tid % NA;
  const bool act2 = (tid < NE * NA);

  __shared__ __align__(16) float s_seq[NE][NA][HD];
  __shared__ float s_amp[NA];
  __shared__ float s_er[NE][NA];
  __shared__ float s_red[256];
  __shared__ float s_scal[8];
  __shared__ float s_aeinv[HD];
  __shared__ float convA[NE * CPAD * CSTR];
  __shared__ float convB[NE * CPAD * CSTR];
  __shared__ float s_y[NE][H2];
  __shared__ float s_ampr[NE];
  __shared__ float s_eA[24 * CSTR];
  __shared__ float s_eB[24 * CSTR];
  __shared__ float s_y2[H2];
  __shared__ float s_cewt[32 * H2];

  float cwr[8], wir[2];
  #pragma unroll
  for (int j = 0; j < 8; j++) cwr[j] = conv_a_w[j * 64 + lane];
  #pragma unroll
  for (int j = 0; j < 2; j++) wir[j] = Wi[j * 64 + lane];

  for (int s = tid; s < 512; s += 256) {
    int o = s >> 5, i = (s >> 1) & 15, k = s & 1;
    s_cewt[(i * 2 + k) * 16 + o] = conv_e_w[s];
  }
  for (int i = tid; i < NE*NA*HD/4; i += 256)
    ((float4*)s_seq)[i] = ((const float4*)seq_ws)[i];
  if (tid < NA) s_amp[tid] = (float)ix_a[tid];
  float rae2 = act2 ? rae_ws[tid] : 0.f;
  __syncthreads();

  // amp_ae / bias_ae
  {
    float sum = block_reduce_sum(act2 ? rae2 : 0.f, s_red, tid);
    float mean = sum / (float)(NE * NA);
    float d = act2 ? (rae2 - mean) : 0.f;
    float ssum = block_reduce_sum(d * d, s_red, tid);
    if (tid == 0) { s_scal[0] = sqrtf(ssum / (float)(NE * NA - 1)); s_scal[1] = mean; }
  }
  __syncthreads();

  // ae_inv last row: Cramer (all static indices, registers only)
  if (tid == 0) {
    float ew[32];
    #pragma unroll
    for (int i = 0; i < 32; i++) ew[i] = emb_w[i];
    double m[4][4];
    #pragma unroll
    for (int i = 0; i < 4; i++)
      #pragma unroll
      for (int j = 0; j < 4; j++) {
        double s = 0.0;
        #pragma unroll
        for (int hh = 0; hh < HD; hh++) s += (double)ew[hh*4+i] * (double)ew[hh*4+j];
        m[i][j] = s;
      }
    double mn0 = det3(m[0][1],m[0][2],m[0][3], m[1][1],m[1][2],m[1][3], m[2][1],m[2][2],m[2][3]);
    double mn1 = det3(m[0][0],m[0][2],m[0][3], m[1][0],m[1][2],m[1][3], m[2][0],m[2][2],m[2][3]);
    double mn2 = det3(m[0][0],m[0][1],m[0][3], m[1][0],m[1][1],m[1][3], m[2][0],m[2][1],m[2][3]);
    double mn3 = det3(m[0][0],m[0][1],m[0][2], m[1][0],m[1][1],m[1][2], m[2][0],m[2][1],m[2][2]);
    double det = -m[3][0]*mn0 + m[3][1]*mn1 - m[3][2]*mn2 + m[3][3]*mn3;
    double y0 = -mn0/det, y1 = mn1/det, y2 = -mn2/det, y3 = mn3/det;
    #pragma unroll
    for (int hh = 0; hh < HD; hh++)
      s_aeinv[hh] = (float)(y0*ew[hh*4+0] + y1*ew[hh*4+1] + y2*ew[hh*4+2] + y3*ew[hh*4+3]);
  }
  __syncthreads();

  // r projection + normalization + exp(-r)
  float rv = 0.f;
  if (act2) {
    #pragma unroll
    for (int hh = 0; hh < HD; hh++) rv += s_aeinv[hh] * s_seq[b][a2i][hh];
  }
  {
    float sum = block_reduce_sum(act2 ? rv : 0.f, s_red, tid);
    float rm = sum / (float)(NE * NA);
    float d = act2 ? (rv - rm) : 0.f;
    float ssum = block_reduce_sum(d * d, s_red, tid);
    float rs = sqrtf(ssum / (float)(NE * NA - 1));
    if (act2) {
      float rr = s_scal[0] * (rv - rm) / rs + s_scal[1];
      s_er[b][a2i] = expf(-rr);
    }
  }
  __syncthreads();

  // Wi projection into conv buffer [bb][pos][chan]
  if (act2) {
    float e2 = s_er[b][a2i] * s_amp[a2i];
    float4 sq0 = *(const float4*)&s_seq[b][a2i][0];
    float4 sq1 = *(const float4*)&s_seq[b][a2i][4];
    float tv[HD] = { e2*sq0.x, e2*sq0.y, e2*sq0.z, e2*sq0.w,
                     e2*sq1.x, e2*sq1.y, e2*sq1.z, e2*sq1.w };
    #pragma unroll
    for (int o = 0; o < H2; o++) {
      float s = bi[o];
      #pragma unroll
      for (int hh = 0; hh < HD; hh++) s += tv[hh] * RL(wir[(o * 8 + hh) >> 6], (o * 8 + hh) & 63);
      convA[(b * CPAD + a2i) * CSTR + o] = s;
    }
  }
  for (int z = tid; z < NE * H2; z += 256)
    convA[((z >> 4) * CPAD + 11) * CSTR + (z & 15)] = 0.f;
  __syncthreads();

  // y (mean over atoms), amp_r
  for (int idx = tid; idx < NE * H2; idx += 256) {
    int bb = idx >> 4, o = idx & 15;
    float s = 0.f;
    for (int aa = 0; aa < NA; aa++) s += convA[(bb * CPAD + aa) * CSTR + o];
    s_y[bb][o] = s / (float)NA;
  }
  if (tid < NE) {
    float s = 0.f;
    for (int aa = 0; aa < NA; aa++) s += s_er[tid][aa];
    s_ampr[tid] = s / (float)NA;
  }
  __syncthreads();

  // atom conv pyramid
  float* pin = convA;
  float* pout = convB;
  int L = NA;
  for (int it = 0; it < 6; it++) {
    int Lo = (L - 1) / 2 + 1;
    for (int pos = tid; pos < NE * Lo; pos += 256) {
      int bb = pos / Lo, j = pos - bb * Lo;
      const float* r0 = pin + (bb * CPAD + 2 * j) * CSTR;
      const float* r1 = r0 + CSTR;
      float x0[16], x1[16];
      #pragma unroll
      for (int i = 0; i < 16; i++) { x0[i] = r0[i]; x1[i] = r1[i]; }
      float* wrow = pout + (bb * CPAD + j) * CSTR;
      #pragma unroll
      for (int o = 0; o < 16; o++) {
        float acc = 0.f;
        #pragma unroll
        for (int i = 0; i < 16; i++) {
          acc += x0[i] * RL(cwr[((o * 16 + i) * 2) >> 6], ((o * 16 + i) * 2) & 63)
               + x1[i] * RL(cwr[((o * 16 + i) * 2 + 1) >> 6], ((o * 16 + i) * 2 + 1) & 63);
        }
        wrow[o] = acc;
      }
    }
    for (int z = tid; z < NE * H2; z += 256)
      pout[((z >> 4) * CPAD + Lo) * CSTR + (z & 15)] = 0.f;
    __syncthreads();
    float* t = pin; pin = pout; pout = t;
    L = Lo;
  }

  // per-electron LN (template-unrolled), amp_r scaling -> electron buffer
  if (tid < NE) {
    float t[H2], oo[H2];
    #pragma unroll
    for (int o = 0; o < H2; o++) t[o] = s_y[tid][o] + pin[(tid * CPAD) * CSTR + o];
    ln_t<H2>(t, ni_g, ni_b, oo);
    float ar = s_ampr[tid];
    #pragma unroll
    for (int o = 0; o < H2; o++) s_eA[tid * CSTR + o] = ar * oo[o];
  }
  if (tid < H2) s_eA[NE * CSTR + tid] = 0.f;
  __syncthreads();
  if (tid < H2) {
    float s = 0.f;
    for (int bb = 0; bb < NE; bb++) s += s_eA[bb * CSTR + tid];
    s_y2[tid] = s / (float)NE;
  }
  if (tid == 0) {
    float s = 0.f;
    for (int bb = 0; bb < NE; bb++) s += s_ampr[bb];
    s_scal[4] = s / (float)NE;   // amp_r2
  }
  __syncthreads();

  // electron conv pyramid
  float* pinE = s_eA;
  float* poutE = s_eB;
  L = NE;
  for (int it = 0; it < 11; it++) {
    int Lo = (L - 1) / 2 + 1;
    for (int idx = tid; idx < Lo * H2; idx += 256) {
      int j = idx >> 4, o = idx & 15;
      const float* r0 = pinE + (2 * j) * CSTR;
      const float* r1 = r0 + CSTR;
      float acc = 0.f;
      #pragma unroll
      for (int i = 0; i < 16; i++)
        acc += r0[i] * s_cewt[(i * 2) * 16 + o] + r1[i] * s_cewt[(i * 2 + 1) * 16 + o];
      poutE[j * CSTR + o] = acc;
    }
    if (tid < H2) poutE[Lo * CSTR + tid] = 0.f;
    __syncthreads();
    float* t = pinE; pinE = poutE; poutE = t;
    L = Lo;
  }

  if (tid == 0) {
    float t[H2], oo[H2];
    #pragma unroll
    for (int o = 0; o < H2; o++) t[o] = s_y2[o] + pinE[o];
    ln_t<H2>(t, ni_g, ni_b, oo);
    float a2 = s_scal[4];
    #pragma unroll
    for (int o = 0; o < H2; o++) xf_out[o] = a2 * oo[o];
  }
}

// ============ psi: memory-bound output projection ============
__global__ __launch_bounds__(256) void psi_kernel(
    const float* __restrict__ Wout, const float* __restrict__ bout,
    const float* __restrict__ xf, float* __restrict__ out, QCS cs, int n)
{
  __shared__ float s_xf[H2];
  if (threadIdx.x < H2) s_xf[threadIdx.x] = xf[threadIdx.x];
  __syncthreads();
  int lane = threadIdx.x & 63;
  int waveBase = blockIdx.x * 256 + (threadIdx.x & ~63);
  if (waveBase >= n) return;
  const float4* W4 = (const float4*)Wout + (size_t)waveBase * 4;
  int q = lane & 3;
  float4 xq = make_float4(s_xf[q * 4], s_xf[q * 4 + 1], s_xf[q * 4 + 2], s_xf[q * 4 + 3]);
  #pragma unroll
  for (int j = 0; j < 4; j++) {
    float4 w = W4[j * 64 + lane];
    float p = w.x * xq.x + w.y * xq.y + w.z * xq.z + w.w * xq.w;
    p += __shfl_xor(p, 1, 64);
    p += __shfl_xor(p, 2, 64);
    if (q == 0) {
      int row = waveBase + j * 16 + (lane >> 2);
      float acc = bout[row] + p;
      unsigned int ii = (unsigned int)row;
      float pr = (float)(1 << (QN / 2));
      #pragma unroll
      for (int qb = 0; qb < QN; qb++)
        pr *= ((ii >> (QN - 1 - qb)) & 1u) ? cs.s[qb] : cs.c[qb];
      out[row] = acc + pr;
    }
  }
}

extern "C" void kernel_launch(void* const* d_in, const int* in_sizes, int n_in,
                              void* d_out, int out_size, void* d_ws, size_t ws_size,
                              hipStream_t stream) {
  const float* pos_a   = (const float*)d_in[0];
  const int*   ix_a    = (const int*)d_in[1];
  const int*   pos_ix  = (const int*)d_in[2];
  const int*   atom_ix = (const int*)d_in[3];
  const float* rpos_w  = (const float*)d_in[4];
  const float* emb_w   = (const float*)d_in[5];
  const float* emb_b   = (const float*)d_in[6];
  const float* Wq = (const float*)d_in[7];   const float* bq = (const float*)d_in[8];
  const float* Wk = (const float*)d_in[9];   const float* bk = (const float*)d_in[10];
  const float* Wv = (const float*)d_in[11];  const float* bv = (const float*)d_in[12];
  const float* Wo = (const float*)d_in[13];  const float* bo = (const float*)d_in[14];
  const float* W1 = (const float*)d_in[15];  const float* b1 = (const float*)d_in[16];
  const float* W2 = (const float*)d_in[17];  const float* b2 = (const float*)d_in[18];
  const float* ln1_g = (const float*)d_in[19]; const float* ln1_b = (const float*)d_in[20];
  const float* ln2_g = (const float*)d_in[21]; const float* ln2_b = (const float*)d_in[22];
  const float* Wi = (const float*)d_in[23];  const float* bi = (const float*)d_in[24];
  const float* ni_g = (const float*)d_in[25]; const float* ni_b = (const float*)d_in[26];
  const float* conv_a_w = (const float*)d_in[27];
  const float* conv_e_w = (const float*)d_in[28];
  const float* Wout = (const float*)d_in[29];
  const float* bout = (const float*)d_in[30];

  float* ws = (float*)d_ws;
  float* xf      = ws;                    // [16]
  int*   counter = (int*)(ws + 32);       // [1]
  float* seq_ws  = ws + 64;               // [22*11*8]
  float* rae_ws  = ws + 64 + NE*NA*HD;    // [22*11]

  hipMemsetAsync(counter, 0, sizeof(int), stream);

  net_kernel<<<NE, 256, 0, stream>>>(pos_a, ix_a, pos_ix, atom_ix, rpos_w,
      emb_w, emb_b, Wq, bq, Wk, bk, Wv, bv, Wo, bo, W1, b1, W2, b2,
      ln1_g, ln1_b, ln2_g, ln2_b, Wi, bi, ni_g, ni_b, conv_a_w, conv_e_w,
      seq_ws, rae_ws, counter, xf);

  QCS cs;
  int n_e = in_sizes[2];
  for (int q = 0; q < QN; q++) {
    float hf = (q < n_e && (q % 2 == 0)) ? (float)M_PI : 0.0f;
    cs.c[q] = cosf(0.5f * hf);
    cs.s[q] = sinf(0.5f * hf);
  }

  int n = out_size;
  int blocks = (n + 255) / 256;
  psi_kernel<<<blocks, 256, 0, stream>>>(Wout, bout, xf, (float*)d_out, cs, n);
}